// Round 4
// baseline (183.045 us; speedup 1.0000x reference)
//
#include <hip/hip_runtime.h>
#include <hip/hip_bf16.h>

typedef __attribute__((ext_vector_type(8))) short short8;
typedef __attribute__((ext_vector_type(4))) short short4v;
typedef __attribute__((ext_vector_type(4))) float f32x4;

#define TT 4096
#define DM 1024
#define NH 16
#define NPROJ 1280   // 128 qs + 128 ks + 256 qg + 256 kg + 512 v
#define DATTN 512

static __device__ __forceinline__ short f2bf(float f) {
  __hip_bfloat16 h = __float2bfloat16(f);
  return *reinterpret_cast<short*>(&h);
}
static __device__ __forceinline__ float bf2f(__hip_bfloat16 h) { return __bfloat162float(h); }

// ---------------- fp32 -> bf16 convert (x, out_w) ----------------
__global__ __launch_bounds__(256) void k_f32_to_bf16(const float* __restrict__ in,
                                                     __hip_bfloat16* __restrict__ out, int n4) {
  int i = blockIdx.x * blockDim.x + threadIdx.x;
  if (i >= n4) return;
  float4 v = reinterpret_cast<const float4*>(in)[i];
  short4v o;
  o[0] = f2bf(v.x); o[1] = f2bf(v.y); o[2] = f2bf(v.z); o[3] = f2bf(v.w);
  reinterpret_cast<short4v*>(out)[i] = o;
}

// ---------------- concat 5 weight matrices into (1280,1024) bf16 ----------------
__global__ __launch_bounds__(256) void k_pack_wcat(const float* __restrict__ qs,
    const float* __restrict__ ks, const float* __restrict__ qg, const float* __restrict__ kg,
    const float* __restrict__ vw, __hip_bfloat16* __restrict__ w, int n4) {
  int i = blockIdx.x * blockDim.x + threadIdx.x;
  if (i >= n4) return;
  int idx = i * 4;
  int row = idx >> 10;
  int col = idx & 1023;
  const float* src;
  if (row < 128)      src = qs + (size_t)row * DM;
  else if (row < 256) src = ks + (size_t)(row - 128) * DM;
  else if (row < 512) src = qg + (size_t)(row - 256) * DM;
  else if (row < 768) src = kg + (size_t)(row - 512) * DM;
  else                src = vw + (size_t)(row - 768) * DM;
  float4 v = *reinterpret_cast<const float4*>(src + col);
  short4v o;
  o[0] = f2bf(v.x); o[1] = f2bf(v.y); o[2] = f2bf(v.z); o[3] = f2bf(v.w);
  *reinterpret_cast<short4v*>(w + idx) = o;
}

// ---------------- bf16 GEMM, B^T layout: C[m][n] = sum_k A[m][k]*B[n][k] ----------------
template<int OUT_BF16>
__global__ __launch_bounds__(256) void k_gemm_bt(const __hip_bfloat16* __restrict__ A,
    const __hip_bfloat16* __restrict__ B, void* __restrict__ Cv, int M, int N, int K) {
  __shared__ alignas(16) __hip_bfloat16 lA[128 * 32];
  __shared__ alignas(16) __hip_bfloat16 lB[128 * 32];
  const int tid = threadIdx.x;
  const int lane = tid & 63;
  const int wid = tid >> 6;
  const int m0 = blockIdx.x * 128, n0 = blockIdx.y * 128;
  const int wm = (wid >> 1) * 64, wn = (wid & 1) * 64;
  const int srow = tid >> 2;          // 0..63
  const int scol = (tid & 3) * 8;     // bf16 elements
  const int fr = lane & 15, fk = (lane >> 4) * 8;
  f32x4 acc[4][4];
  const f32x4 zz = {0.f, 0.f, 0.f, 0.f};
#pragma unroll
  for (int m = 0; m < 4; ++m)
#pragma unroll
    for (int n = 0; n < 4; ++n) acc[m][n] = zz;

  for (int kt = 0; kt < K; kt += 32) {
    __syncthreads();
    {
      const __hip_bfloat16* ga0 = A + (size_t)(m0 + srow) * K + kt + scol;
      const __hip_bfloat16* ga1 = A + (size_t)(m0 + 64 + srow) * K + kt + scol;
      const __hip_bfloat16* gb0 = B + (size_t)(n0 + srow) * K + kt + scol;
      const __hip_bfloat16* gb1 = B + (size_t)(n0 + 64 + srow) * K + kt + scol;
      __builtin_amdgcn_global_load_lds((const __attribute__((address_space(1))) void*)ga0,
          (__attribute__((address_space(3))) void*)(lA + srow * 32 + scol), 16, 0, 0);
      __builtin_amdgcn_global_load_lds((const __attribute__((address_space(1))) void*)ga1,
          (__attribute__((address_space(3))) void*)(lA + (64 + srow) * 32 + scol), 16, 0, 0);
      __builtin_amdgcn_global_load_lds((const __attribute__((address_space(1))) void*)gb0,
          (__attribute__((address_space(3))) void*)(lB + srow * 32 + scol), 16, 0, 0);
      __builtin_amdgcn_global_load_lds((const __attribute__((address_space(1))) void*)gb1,
          (__attribute__((address_space(3))) void*)(lB + (64 + srow) * 32 + scol), 16, 0, 0);
    }
    __syncthreads();
    short8 af[4], bfr[4];
#pragma unroll
    for (int m = 0; m < 4; ++m)
      af[m] = *reinterpret_cast<const short8*>(lA + (wm + m * 16 + fr) * 32 + fk);
#pragma unroll
    for (int n = 0; n < 4; ++n)
      bfr[n] = *reinterpret_cast<const short8*>(lB + (wn + n * 16 + fr) * 32 + fk);
#pragma unroll
    for (int m = 0; m < 4; ++m)
#pragma unroll
      for (int n = 0; n < 4; ++n)
        acc[m][n] = __builtin_amdgcn_mfma_f32_16x16x32_bf16(af[m], bfr[n], acc[m][n], 0, 0, 0);
  }
  const int cr = (lane >> 4) * 4, cc = lane & 15;
#pragma unroll
  for (int m = 0; m < 4; ++m)
#pragma unroll
    for (int n = 0; n < 4; ++n)
#pragma unroll
      for (int j = 0; j < 4; ++j) {
        const int row = m0 + wm + m * 16 + cr + j;
        const int col = n0 + wn + n * 16 + cc;
        if (OUT_BF16)
          ((__hip_bfloat16*)Cv)[(size_t)row * N + col] = __float2bfloat16(acc[m][n][j]);
        else
          ((float*)Cv)[(size_t)row * N + col] = acc[m][n][j];
      }
}

// ---------------- RoPE + pack Q/K (H,T,32) and V^T (H,32,T) ----------------
// qscale folds 1/sqrt(24) * exp(logit_scale) * log2(e)  (softmax uses exp2)
__global__ __launch_bounds__(256) void k_rope_pack(const __hip_bfloat16* __restrict__ proj,
    const float* __restrict__ ls, const int* __restrict__ posp,
    __hip_bfloat16* __restrict__ Qp, __hip_bfloat16* __restrict__ Kp,
    __hip_bfloat16* __restrict__ Vt) {
  const int gid = blockIdx.x * blockDim.x + threadIdx.x;  // T*NH, t fastest
  const int t = gid & (TT - 1);
  const int h = gid >> 12;
  const __hip_bfloat16* pr = proj + (size_t)t * NPROJ;
  const float qscale = 0.20412414523193154f * 1.4426950408889634f * __expf(ls[h]);
  const float pos = (float)(t + posp[0]);
  const float invf[8] = {1.0f, 0.31622776601683794f, 0.1f, 0.031622776601683794f,
                         0.01f, 0.0031622776601683794f, 0.001f, 0.00031622776601683794f};
  short8 qv[4], kv[4];
  const short8 z8 = {0, 0, 0, 0, 0, 0, 0, 0};
  qv[3] = z8; kv[3] = z8;
#pragma unroll
  for (int i = 0; i < 8; ++i) {
    qv[0][i] = f2bf(bf2f(pr[h * 8 + i]) * qscale);
    kv[0][i] = f2bf(bf2f(pr[128 + h * 8 + i]));
  }
#pragma unroll
  for (int i = 0; i < 8; ++i) {
    const float ang = pos * invf[i];
    float ss, cc;
    __sincosf(ang, &ss, &cc);
    const float x1q = bf2f(pr[256 + h * 16 + i]), x2q = bf2f(pr[256 + h * 16 + 8 + i]);
    const float x1k = bf2f(pr[512 + h * 16 + i]), x2k = bf2f(pr[512 + h * 16 + 8 + i]);
    qv[1][i] = f2bf((x1q * cc - x2q * ss) * qscale);
    qv[2][i] = f2bf((x1q * ss + x2q * cc) * qscale);
    kv[1][i] = f2bf(x1k * cc - x2k * ss);
    kv[2][i] = f2bf(x1k * ss + x2k * cc);
  }
  short8* qdst = reinterpret_cast<short8*>(Qp + ((size_t)h * TT + t) * 32);
  short8* kdst = reinterpret_cast<short8*>(Kp + ((size_t)h * TT + t) * 32);
#pragma unroll
  for (int p = 0; p < 4; ++p) { qdst[p] = qv[p]; kdst[p] = kv[p]; }
#pragma unroll
  for (int i = 0; i < 32; ++i)
    Vt[((size_t)h * 32 + i) * TT + t] = pr[768 + h * 32 + i];
}

// ---------------- causal flash attention, KV-split x2, O^T epilogue ----------------
// 4096 blocks x 2 waves. Wave tasks: (r, half). Block sub pairs (sub, half0) with
// (255-sub, half1) -> every block ~32-33 KV tiles. Partials (O,m,l) to workspace.
// mfma(K,Q): lane owns q-row q0+c (c=lane&15); stats uniform across g after xor16/32.
// PV as O^T = mfma(V^T, P^T): C gives O[q=c][d=g*4+j] -> alpha & 1/l all in-lane.
__global__ __launch_bounds__(128) void k_attn(const __hip_bfloat16* __restrict__ Qp,
    const __hip_bfloat16* __restrict__ Kp, const __hip_bfloat16* __restrict__ Vt,
    float* __restrict__ po, float* __restrict__ pm, float* __restrict__ pl) {
  __shared__ alignas(16) __hip_bfloat16 Plds[2][16][72];
  const int lin = blockIdx.x;          // 0..4095
  const int xcd = lin & 7;
  const int idx = lin >> 3;            // 0..511
  const int h = xcd * 2 + (idx >> 8);  // 2 heads per XCD (K/V fits 4MiB L2)
  const int sub = idx & 255;
  const int tid = threadIdx.x;
  const int lane = tid & 63, w = tid >> 6;
  const int r = w ? (255 - sub) : sub; // 16-row q-tile index 0..255
  const int nt = (r >> 2) + 1;
  const int nt0 = (nt + 1) >> 1;
  const int tbeg = w ? nt0 : 0;
  const int tend = w ? nt : nt0;
  const int q0 = r * 16;
  const int g = lane >> 4, c = lane & 15;
  const short8 qf = *reinterpret_cast<const short8*>(Qp + ((size_t)h * TT + q0 + c) * 32 + 8 * g);
  f32x4 o0 = {0.f, 0.f, 0.f, 0.f}, o1 = {0.f, 0.f, 0.f, 0.f};
  const f32x4 zz = {0.f, 0.f, 0.f, 0.f};
  float mst = -1e30f, lsum = 0.f;

  const __hip_bfloat16* pkn = Kp + (size_t)h * TT * 32 + (size_t)(tbeg * 64 + c) * 32 + 8 * g;
  const __hip_bfloat16* pv  = Vt + ((size_t)h * 32 + c) * TT + tbeg * 64 + 8 * g;
  const __hip_bfloat16* pv2 = pv + (size_t)16 * TT;

  short8 kf[4];
  if (tbeg < tend) {
#pragma unroll
    for (int ct = 0; ct < 4; ++ct)
      kf[ct] = *reinterpret_cast<const short8*>(pkn + ct * 512);
    pkn += 2048;
  }

  for (int it = tbeg; it < tend; ++it) {
    // V loads for this tile (early issue)
    const short8 v00 = *reinterpret_cast<const short8*>(pv);
    const short8 v01 = *reinterpret_cast<const short8*>(pv + 32);
    const short8 v10 = *reinterpret_cast<const short8*>(pv2);
    const short8 v11 = *reinterpret_cast<const short8*>(pv2 + 32);
    pv += 64; pv2 += 64;
    // K prefetch for next tile
    short8 kn[4];
    if (it + 1 < tend) {
#pragma unroll
      for (int ct = 0; ct < 4; ++ct)
        kn[ct] = *reinterpret_cast<const short8*>(pkn + ct * 512);
      pkn += 2048;
    }
    f32x4 s[4];
#pragma unroll
    for (int ct = 0; ct < 4; ++ct)
      s[ct] = __builtin_amdgcn_mfma_f32_16x16x32_bf16(kf[ct], qf, zz, 0, 0, 0);  // swapped
    if (it == nt - 1) {  // diagonal tile: causal mask (k > q)
      const int kv0 = it * 64;
#pragma unroll
      for (int ct = 0; ct < 4; ++ct)
#pragma unroll
        for (int j = 0; j < 4; ++j)
          if (kv0 + ct * 16 + g * 4 + j > q0 + c) s[ct][j] = -1e30f;
    }
    // row max: 15 in-lane + 2 xor-shuffles (uniform across g afterwards)
    float pm_ = s[0][0];
#pragma unroll
    for (int ct = 0; ct < 4; ++ct)
#pragma unroll
      for (int j = 0; j < 4; ++j) pm_ = fmaxf(pm_, s[ct][j]);
    pm_ = fmaxf(pm_, __shfl_xor(pm_, 16, 64));
    pm_ = fmaxf(pm_, __shfl_xor(pm_, 32, 64));
    const float nm = fmaxf(mst, pm_);
    float psum[4];
#pragma unroll
    for (int ct = 0; ct < 4; ++ct) {
#pragma unroll
      for (int j = 0; j < 4; ++j) s[ct][j] = exp2f(s[ct][j] - nm);
      psum[ct] = (s[ct][0] + s[ct][1]) + (s[ct][2] + s[ct][3]);
    }
    float sum = (psum[0] + psum[1]) + (psum[2] + psum[3]);
    sum += __shfl_xor(sum, 16, 64);
    sum += __shfl_xor(sum, 32, 64);
    const float alpha = exp2f(mst - nm);   // uniform across g for row c
    lsum = lsum * alpha + sum;
    mst = nm;
#pragma unroll
    for (int j = 0; j < 4; ++j) { o0[j] *= alpha; o1[j] *= alpha; }
    // P -> LDS (packed pairs), per-wave private slice, no barrier
#pragma unroll
    for (int ct = 0; ct < 4; ++ct)
#pragma unroll
      for (int jp = 0; jp < 2; ++jp) {
        const unsigned lo = (unsigned short)f2bf(s[ct][2 * jp]);
        const unsigned hi = (unsigned short)f2bf(s[ct][2 * jp + 1]);
        *reinterpret_cast<unsigned*>(&Plds[w][c][ct * 16 + g * 4 + 2 * jp]) = lo | (hi << 16);
      }
    const short8 pf0 = *reinterpret_cast<const short8*>(&Plds[w][c][8 * g]);
    const short8 pf1 = *reinterpret_cast<const short8*>(&Plds[w][c][32 + 8 * g]);
    // O^T: A = V^T fragment (v loads), B = P^T fragment (same LDS reads)
    o0 = __builtin_amdgcn_mfma_f32_16x16x32_bf16(v00, pf0, o0, 0, 0, 0);
    o0 = __builtin_amdgcn_mfma_f32_16x16x32_bf16(v01, pf1, o0, 0, 0, 0);
    o1 = __builtin_amdgcn_mfma_f32_16x16x32_bf16(v10, pf0, o1, 0, 0, 0);
    o1 = __builtin_amdgcn_mfma_f32_16x16x32_bf16(v11, pf1, o1, 0, 0, 0);
#pragma unroll
    for (int ct = 0; ct < 4; ++ct) kf[ct] = kn[ct];
  }
  // write partials: O[q=c][d=g*4+j] (+16 for o1), m/l per row c
  const int pidx = ((h * 256 + r) * 2 + w);
  float* pob = po + (size_t)pidx * 512 + c * 32 + g * 4;
  *reinterpret_cast<f32x4*>(pob) = o0;
  *reinterpret_cast<f32x4*>(pob + 16) = o1;
  if (g == 0) {
    pm[pidx * 16 + c] = mst;
    pl[pidx * 16 + c] = lsum;
  }
}

// ---------------- merge KV-split halves, write Ob (bf16) ----------------
__global__ __launch_bounds__(256) void k_merge(const float* __restrict__ po,
    const float* __restrict__ pm, const float* __restrict__ pl,
    __hip_bfloat16* __restrict__ Ob) {
  const int i = blockIdx.x * 256 + threadIdx.x;   // 262144 total
  const int d8 = (i & 3) * 8;
  const int q = (i >> 2) & 15;
  const int qt = (i >> 6) & 255;
  const int h = i >> 14;
  const int p0 = (h * 256 + qt) * 2;
  const float m0 = pm[p0 * 16 + q], m1 = pm[(p0 + 1) * 16 + q];
  const float l0 = pl[p0 * 16 + q], l1 = pl[(p0 + 1) * 16 + q];
  const float m = fmaxf(m0, m1);
  const float w0 = exp2f(m0 - m), w1 = exp2f(m1 - m);
  const float inv = 1.0f / (l0 * w0 + l1 * w1);
  const float* a = po + (size_t)p0 * 512 + q * 32 + d8;
  const float* b = a + 512;
  float4 a0 = *reinterpret_cast<const float4*>(a);
  float4 a1 = *reinterpret_cast<const float4*>(a + 4);
  float4 b0 = *reinterpret_cast<const float4*>(b);
  float4 b1 = *reinterpret_cast<const float4*>(b + 4);
  short8 o;
  o[0] = f2bf((a0.x * w0 + b0.x * w1) * inv);
  o[1] = f2bf((a0.y * w0 + b0.y * w1) * inv);
  o[2] = f2bf((a0.z * w0 + b0.z * w1) * inv);
  o[3] = f2bf((a0.w * w0 + b0.w * w1) * inv);
  o[4] = f2bf((a1.x * w0 + b1.x * w1) * inv);
  o[5] = f2bf((a1.y * w0 + b1.y * w1) * inv);
  o[6] = f2bf((a1.z * w0 + b1.z * w1) * inv);
  o[7] = f2bf((a1.w * w0 + b1.w * w1) * inv);
  *reinterpret_cast<short8*>(Ob + (size_t)(qt * 16 + q) * DATTN + h * 32 + d8) = o;
}

extern "C" void kernel_launch(void* const* d_in, const int* in_sizes, int n_in,
                              void* d_out, int out_size, void* d_ws, size_t ws_size,
                              hipStream_t stream) {
  const float* x   = (const float*)d_in[0];
  const float* qsw = (const float*)d_in[1];
  const float* ksw = (const float*)d_in[2];
  const float* qgw = (const float*)d_in[3];
  const float* kgw = (const float*)d_in[4];
  const float* vw  = (const float*)d_in[5];
  const float* ow  = (const float*)d_in[6];
  const float* ls  = (const float*)d_in[7];
  const int* posp  = (const int*)d_in[9];

  size_t off = 0;
  auto alloc = [&](size_t bytes) {
    char* p = (char*)d_ws + off;
    off += (bytes + 255) & ~(size_t)255;
    return (void*)p;
  };
  __hip_bfloat16* Xbf  = (__hip_bfloat16*)alloc((size_t)TT * DM * 2);
  __hip_bfloat16* Wcat = (__hip_bfloat16*)alloc((size_t)NPROJ * DM * 2);
  __hip_bfloat16* OW   = (__hip_bfloat16*)alloc((size_t)DM * DATTN * 2);
  __hip_bfloat16* proj = (__hip_bfloat16*)alloc((size_t)TT * NPROJ * 2);
  __hip_bfloat16* Qp   = (__hip_bfloat16*)alloc((size_t)NH * TT * 32 * 2);
  __hip_bfloat16* Kpk  = (__hip_bfloat16*)alloc((size_t)NH * TT * 32 * 2);
  __hip_bfloat16* Vt   = (__hip_bfloat16*)alloc((size_t)NH * 32 * TT * 2);
  __hip_bfloat16* Ob   = (__hip_bfloat16*)alloc((size_t)TT * DATTN * 2);
  float* PO = (float*)alloc((size_t)NH * 256 * 2 * 512 * 4);
  float* PM = (float*)alloc((size_t)NH * 256 * 2 * 16 * 4);
  float* PL = (float*)alloc((size_t)NH * 256 * 2 * 16 * 4);

  k_f32_to_bf16<<<dim3((TT * DM / 4) / 256), 256, 0, stream>>>(x, Xbf, TT * DM / 4);
  k_f32_to_bf16<<<dim3((DM * DATTN / 4) / 256), 256, 0, stream>>>(ow, OW, DM * DATTN / 4);
  k_pack_wcat<<<dim3((NPROJ * DM / 4) / 256), 256, 0, stream>>>(qsw, ksw, qgw, kgw, vw, Wcat,
                                                                NPROJ * DM / 4);
  k_gemm_bt<1><<<dim3(TT / 128, NPROJ / 128), 256, 0, stream>>>(Xbf, Wcat, (void*)proj,
                                                                TT, NPROJ, DM);
  k_rope_pack<<<dim3(TT * NH / 256), 256, 0, stream>>>(proj, ls, posp, Qp, Kpk, Vt);
  k_attn<<<dim3(4096), 128, 0, stream>>>(Qp, Kpk, Vt, PO, PM, PL);
  k_merge<<<dim3(1024), 256, 0, stream>>>(PO, PM, PL, Ob);
  k_gemm_bt<0><<<dim3(TT / 128, DM / 128), 256, 0, stream>>>(Ob, OW, (void*)d_out,
                                                             TT, DM, DATTN);
}

// Round 5
// 159.484 us; speedup vs baseline: 1.1477x; 1.1477x over previous
//
#include <hip/hip_runtime.h>
#include <hip/hip_bf16.h>

typedef __attribute__((ext_vector_type(8))) short short8;
typedef __attribute__((ext_vector_type(4))) short short4v;
typedef __attribute__((ext_vector_type(4))) float f32x4;

#define TT 4096
#define DM 1024
#define NH 16
#define NPROJ 1280   // 128 qs + 128 ks + 256 qg + 256 kg + 512 v
#define DATTN 512

static __device__ __forceinline__ short f2bf(float f) {
  __hip_bfloat16 h = __float2bfloat16(f);
  return *reinterpret_cast<short*>(&h);
}
static __device__ __forceinline__ float bf2f(__hip_bfloat16 h) { return __bfloat162float(h); }

// ---------------- fp32 -> bf16 convert (x, out_w) ----------------
__global__ __launch_bounds__(256) void k_f32_to_bf16(const float* __restrict__ in,
                                                     __hip_bfloat16* __restrict__ out, int n4) {
  int i = blockIdx.x * blockDim.x + threadIdx.x;
  if (i >= n4) return;
  float4 v = reinterpret_cast<const float4*>(in)[i];
  short4v o;
  o[0] = f2bf(v.x); o[1] = f2bf(v.y); o[2] = f2bf(v.z); o[3] = f2bf(v.w);
  reinterpret_cast<short4v*>(out)[i] = o;
}

// ---------------- concat 5 weight matrices into (1280,1024) bf16 ----------------
__global__ __launch_bounds__(256) void k_pack_wcat(const float* __restrict__ qs,
    const float* __restrict__ ks, const float* __restrict__ qg, const float* __restrict__ kg,
    const float* __restrict__ vw, __hip_bfloat16* __restrict__ w, int n4) {
  int i = blockIdx.x * blockDim.x + threadIdx.x;
  if (i >= n4) return;
  int idx = i * 4;
  int row = idx >> 10;
  int col = idx & 1023;
  const float* src;
  if (row < 128)      src = qs + (size_t)row * DM;
  else if (row < 256) src = ks + (size_t)(row - 128) * DM;
  else if (row < 512) src = qg + (size_t)(row - 256) * DM;
  else if (row < 768) src = kg + (size_t)(row - 512) * DM;
  else                src = vw + (size_t)(row - 768) * DM;
  float4 v = *reinterpret_cast<const float4*>(src + col);
  short4v o;
  o[0] = f2bf(v.x); o[1] = f2bf(v.y); o[2] = f2bf(v.z); o[3] = f2bf(v.w);
  *reinterpret_cast<short4v*>(w + idx) = o;
}

// ---------------- bf16 GEMM, B^T layout: C[m][n] = sum_k A[m][k]*B[n][k] ----------------
template<int OUT_BF16>
__global__ __launch_bounds__(256) void k_gemm_bt(const __hip_bfloat16* __restrict__ A,
    const __hip_bfloat16* __restrict__ B, void* __restrict__ Cv, int M, int N, int K) {
  __shared__ alignas(16) __hip_bfloat16 lA[128 * 32];
  __shared__ alignas(16) __hip_bfloat16 lB[128 * 32];
  const int tid = threadIdx.x;
  const int lane = tid & 63;
  const int wid = tid >> 6;
  const int m0 = blockIdx.x * 128, n0 = blockIdx.y * 128;
  const int wm = (wid >> 1) * 64, wn = (wid & 1) * 64;
  const int srow = tid >> 2;          // 0..63
  const int scol = (tid & 3) * 8;     // bf16 elements
  const int fr = lane & 15, fk = (lane >> 4) * 8;
  f32x4 acc[4][4];
  const f32x4 zz = {0.f, 0.f, 0.f, 0.f};
#pragma unroll
  for (int m = 0; m < 4; ++m)
#pragma unroll
    for (int n = 0; n < 4; ++n) acc[m][n] = zz;

  for (int kt = 0; kt < K; kt += 32) {
    __syncthreads();
    {
      const __hip_bfloat16* ga0 = A + (size_t)(m0 + srow) * K + kt + scol;
      const __hip_bfloat16* ga1 = A + (size_t)(m0 + 64 + srow) * K + kt + scol;
      const __hip_bfloat16* gb0 = B + (size_t)(n0 + srow) * K + kt + scol;
      const __hip_bfloat16* gb1 = B + (size_t)(n0 + 64 + srow) * K + kt + scol;
      __builtin_amdgcn_global_load_lds((const __attribute__((address_space(1))) void*)ga0,
          (__attribute__((address_space(3))) void*)(lA + srow * 32 + scol), 16, 0, 0);
      __builtin_amdgcn_global_load_lds((const __attribute__((address_space(1))) void*)ga1,
          (__attribute__((address_space(3))) void*)(lA + (64 + srow) * 32 + scol), 16, 0, 0);
      __builtin_amdgcn_global_load_lds((const __attribute__((address_space(1))) void*)gb0,
          (__attribute__((address_space(3))) void*)(lB + srow * 32 + scol), 16, 0, 0);
      __builtin_amdgcn_global_load_lds((const __attribute__((address_space(1))) void*)gb1,
          (__attribute__((address_space(3))) void*)(lB + (64 + srow) * 32 + scol), 16, 0, 0);
    }
    __syncthreads();
    short8 af[4], bfr[4];
#pragma unroll
    for (int m = 0; m < 4; ++m)
      af[m] = *reinterpret_cast<const short8*>(lA + (wm + m * 16 + fr) * 32 + fk);
#pragma unroll
    for (int n = 0; n < 4; ++n)
      bfr[n] = *reinterpret_cast<const short8*>(lB + (wn + n * 16 + fr) * 32 + fk);
#pragma unroll
    for (int m = 0; m < 4; ++m)
#pragma unroll
      for (int n = 0; n < 4; ++n)
        acc[m][n] = __builtin_amdgcn_mfma_f32_16x16x32_bf16(af[m], bfr[n], acc[m][n], 0, 0, 0);
  }
  const int cr = (lane >> 4) * 4, cc = lane & 15;
#pragma unroll
  for (int m = 0; m < 4; ++m)
#pragma unroll
    for (int n = 0; n < 4; ++n)
#pragma unroll
      for (int j = 0; j < 4; ++j) {
        const int row = m0 + wm + m * 16 + cr + j;
        const int col = n0 + wn + n * 16 + cc;
        if (OUT_BF16)
          ((__hip_bfloat16*)Cv)[(size_t)row * N + col] = __float2bfloat16(acc[m][n][j]);
        else
          ((float*)Cv)[(size_t)row * N + col] = acc[m][n][j];
      }
}

// ---------------- RoPE + pack Q/K (H,T,32) and V^T (H,32,T) ----------------
// qscale folds 1/sqrt(24) * exp(logit_scale) * log2(e)  (softmax uses exp2)
__global__ __launch_bounds__(256) void k_rope_pack(const __hip_bfloat16* __restrict__ proj,
    const float* __restrict__ ls, const int* __restrict__ posp,
    __hip_bfloat16* __restrict__ Qp, __hip_bfloat16* __restrict__ Kp,
    __hip_bfloat16* __restrict__ Vt) {
  const int gid = blockIdx.x * blockDim.x + threadIdx.x;  // T*NH, t fastest
  const int t = gid & (TT - 1);
  const int h = gid >> 12;
  const __hip_bfloat16* pr = proj + (size_t)t * NPROJ;
  const float qscale = 0.20412414523193154f * 1.4426950408889634f * __expf(ls[h]);
  const float pos = (float)(t + posp[0]);
  const float invf[8] = {1.0f, 0.31622776601683794f, 0.1f, 0.031622776601683794f,
                         0.01f, 0.0031622776601683794f, 0.001f, 0.00031622776601683794f};
  short8 qv[4], kv[4];
  const short8 z8 = {0, 0, 0, 0, 0, 0, 0, 0};
  qv[3] = z8; kv[3] = z8;
#pragma unroll
  for (int i = 0; i < 8; ++i) {
    qv[0][i] = f2bf(bf2f(pr[h * 8 + i]) * qscale);
    kv[0][i] = f2bf(bf2f(pr[128 + h * 8 + i]));
  }
#pragma unroll
  for (int i = 0; i < 8; ++i) {
    const float ang = pos * invf[i];
    float ss, cc;
    __sincosf(ang, &ss, &cc);
    const float x1q = bf2f(pr[256 + h * 16 + i]), x2q = bf2f(pr[256 + h * 16 + 8 + i]);
    const float x1k = bf2f(pr[512 + h * 16 + i]), x2k = bf2f(pr[512 + h * 16 + 8 + i]);
    qv[1][i] = f2bf((x1q * cc - x2q * ss) * qscale);
    qv[2][i] = f2bf((x1q * ss + x2q * cc) * qscale);
    kv[1][i] = f2bf(x1k * cc - x2k * ss);
    kv[2][i] = f2bf(x1k * ss + x2k * cc);
  }
  short8* qdst = reinterpret_cast<short8*>(Qp + ((size_t)h * TT + t) * 32);
  short8* kdst = reinterpret_cast<short8*>(Kp + ((size_t)h * TT + t) * 32);
#pragma unroll
  for (int p = 0; p < 4; ++p) { qdst[p] = qv[p]; kdst[p] = kv[p]; }
#pragma unroll
  for (int i = 0; i < 32; ++i)
    Vt[((size_t)h * 32 + i) * TT + t] = pr[768 + h * 32 + i];
}

// ---------------- causal flash attention, zero-shuffle steady state ----------------
// 2048 blocks x 2 waves. Wave w handles q-tile r (w0: sub, w1: 255-sub).
// mfma(K,Q): lane (c,g) owns q-row q0+c; s[ct][j] = P[c][ct*16+g*4+j].
// O^T epilogue: O fragment col = q-row = lane c -> alpha & 1/l in-lane.
// Per-lane partial lsum, reduced ONCE after the loop.
// Defer-max: skip max-reduce + rescale unless in-lane max exceeds mst+8 (exact).
__global__ __launch_bounds__(128) void k_attn(const __hip_bfloat16* __restrict__ Qp,
    const __hip_bfloat16* __restrict__ Kp, const __hip_bfloat16* __restrict__ Vt,
    __hip_bfloat16* __restrict__ Ob) {
  __shared__ alignas(16) __hip_bfloat16 Plds[2][16][72];
  const int lin = blockIdx.x;          // 0..2047
  const int xcd = lin & 7;
  const int idx = lin >> 3;            // 0..255
  const int h = xcd * 2 + (idx >> 7);  // 2 heads per XCD (K/V fits 4MiB L2)
  const int sub = idx & 127;
  const int tid = threadIdx.x;
  const int lane = tid & 63, w = tid >> 6;
  const int r = w ? (255 - sub) : sub; // 16-row q-tile index 0..255
  if (r >= 192) __builtin_amdgcn_s_setprio(1);  // long waves get issue priority
  const int nt = (r >> 2) + 1;
  const int q0 = r * 16;
  const int g = lane >> 4, c = lane & 15;
  const short8 qf = *reinterpret_cast<const short8*>(Qp + ((size_t)h * TT + q0 + c) * 32 + 8 * g);
  f32x4 o0 = {0.f, 0.f, 0.f, 0.f}, o1 = {0.f, 0.f, 0.f, 0.f};
  const f32x4 zz = {0.f, 0.f, 0.f, 0.f};
  float mst = -1e30f, lsum = 0.f;      // lsum is per-lane partial (16 kv/lane/tile)

  const __hip_bfloat16* pkn = Kp + (size_t)h * TT * 32 + (size_t)c * 32 + 8 * g;
  const __hip_bfloat16* pv  = Vt + ((size_t)h * 32 + c) * TT + 8 * g;
  const __hip_bfloat16* pv2 = pv + (size_t)16 * TT;

  short8 kf[4];
#pragma unroll
  for (int ct = 0; ct < 4; ++ct)
    kf[ct] = *reinterpret_cast<const short8*>(pkn + ct * 512);
  pkn += 2048;

  for (int it = 0; it < nt; ++it) {
    // V loads for this tile (early issue)
    const short8 v00 = *reinterpret_cast<const short8*>(pv);
    const short8 v01 = *reinterpret_cast<const short8*>(pv + 32);
    const short8 v10 = *reinterpret_cast<const short8*>(pv2);
    const short8 v11 = *reinterpret_cast<const short8*>(pv2 + 32);
    pv += 64; pv2 += 64;
    // K prefetch for next tile
    short8 kn[4];
    if (it + 1 < nt) {
#pragma unroll
      for (int ct = 0; ct < 4; ++ct)
        kn[ct] = *reinterpret_cast<const short8*>(pkn + ct * 512);
      pkn += 2048;
    }
    f32x4 s[4];
#pragma unroll
    for (int ct = 0; ct < 4; ++ct)
      s[ct] = __builtin_amdgcn_mfma_f32_16x16x32_bf16(kf[ct], qf, zz, 0, 0, 0);  // swapped
    if (it == nt - 1) {  // diagonal tile: causal mask (k > q)
      const int kv0 = it * 64;
#pragma unroll
      for (int ct = 0; ct < 4; ++ct)
#pragma unroll
        for (int j = 0; j < 4; ++j)
          if (kv0 + ct * 16 + g * 4 + j > q0 + c) s[ct][j] = -1e30f;
    }
    // in-lane max over this lane's 16 scores (max3-friendly tree)
    float m01 = fmaxf(fmaxf(s[0][0], s[0][1]), fmaxf(s[0][2], s[0][3]));
    float m23 = fmaxf(fmaxf(s[1][0], s[1][1]), fmaxf(s[1][2], s[1][3]));
    float m45 = fmaxf(fmaxf(s[2][0], s[2][1]), fmaxf(s[2][2], s[2][3]));
    float m67 = fmaxf(fmaxf(s[3][0], s[3][1]), fmaxf(s[3][2], s[3][3]));
    float pm_ = fmaxf(fmaxf(m01, m23), fmaxf(m45, m67));
    if (__any(pm_ > mst + 8.0f)) {     // rare once m stabilizes
      float pm2 = fmaxf(pm_, __shfl_xor(pm_, 16, 64));
      pm2 = fmaxf(pm2, __shfl_xor(pm2, 32, 64));
      const float nm = fmaxf(mst, pm2);
      const float alpha = exp2f(mst - nm);
      mst = nm;
      lsum *= alpha;
#pragma unroll
      for (int j = 0; j < 4; ++j) { o0[j] *= alpha; o1[j] *= alpha; }
    }
    float ts = 0.f;
#pragma unroll
    for (int ct = 0; ct < 4; ++ct) {
#pragma unroll
      for (int j = 0; j < 4; ++j) s[ct][j] = exp2f(s[ct][j] - mst);
      ts += (s[ct][0] + s[ct][1]) + (s[ct][2] + s[ct][3]);
    }
    lsum += ts;
    // P -> LDS (packed pairs), per-wave private slice, no barrier
#pragma unroll
    for (int ct = 0; ct < 4; ++ct)
#pragma unroll
      for (int jp = 0; jp < 2; ++jp) {
        const unsigned lo = (unsigned short)f2bf(s[ct][2 * jp]);
        const unsigned hi = (unsigned short)f2bf(s[ct][2 * jp + 1]);
        *reinterpret_cast<unsigned*>(&Plds[w][c][ct * 16 + g * 4 + 2 * jp]) = lo | (hi << 16);
      }
    const short8 pf0 = *reinterpret_cast<const short8*>(&Plds[w][c][8 * g]);
    const short8 pf1 = *reinterpret_cast<const short8*>(&Plds[w][c][32 + 8 * g]);
    // O^T: A = V^T fragment, B = P^T fragment; C col = q-row = lane c
    o0 = __builtin_amdgcn_mfma_f32_16x16x32_bf16(v00, pf0, o0, 0, 0, 0);
    o0 = __builtin_amdgcn_mfma_f32_16x16x32_bf16(v01, pf1, o0, 0, 0, 0);
    o1 = __builtin_amdgcn_mfma_f32_16x16x32_bf16(v10, pf0, o1, 0, 0, 0);
    o1 = __builtin_amdgcn_mfma_f32_16x16x32_bf16(v11, pf1, o1, 0, 0, 0);
#pragma unroll
    for (int ct = 0; ct < 4; ++ct) kf[ct] = kn[ct];
  }
  // single final lsum reduce across the 4 g-lanes of row c
  lsum += __shfl_xor(lsum, 16, 64);
  lsum += __shfl_xor(lsum, 32, 64);
  const float inv = 1.0f / lsum;
  const int row = q0 + c;
  __hip_bfloat16* dst = Ob + (size_t)row * DATTN + h * 32;
  short4v w0, w1;
#pragma unroll
  for (int j = 0; j < 4; ++j) { w0[j] = f2bf(o0[j] * inv); w1[j] = f2bf(o1[j] * inv); }
  *reinterpret_cast<short4v*>(dst + g * 4) = w0;
  *reinterpret_cast<short4v*>(dst + 16 + g * 4) = w1;
}

extern "C" void kernel_launch(void* const* d_in, const int* in_sizes, int n_in,
                              void* d_out, int out_size, void* d_ws, size_t ws_size,
                              hipStream_t stream) {
  const float* x   = (const float*)d_in[0];
  const float* qsw = (const float*)d_in[1];
  const float* ksw = (const float*)d_in[2];
  const float* qgw = (const float*)d_in[3];
  const float* kgw = (const float*)d_in[4];
  const float* vw  = (const float*)d_in[5];
  const float* ow  = (const float*)d_in[6];
  const float* ls  = (const float*)d_in[7];
  const int* posp  = (const int*)d_in[9];

  size_t off = 0;
  auto alloc = [&](size_t bytes) {
    char* p = (char*)d_ws + off;
    off += (bytes + 255) & ~(size_t)255;
    return (void*)p;
  };
  __hip_bfloat16* Xbf  = (__hip_bfloat16*)alloc((size_t)TT * DM * 2);
  __hip_bfloat16* Wcat = (__hip_bfloat16*)alloc((size_t)NPROJ * DM * 2);
  __hip_bfloat16* OW   = (__hip_bfloat16*)alloc((size_t)DM * DATTN * 2);
  __hip_bfloat16* proj = (__hip_bfloat16*)alloc((size_t)TT * NPROJ * 2);
  __hip_bfloat16* Qp   = (__hip_bfloat16*)alloc((size_t)NH * TT * 32 * 2);
  __hip_bfloat16* Kpk  = (__hip_bfloat16*)alloc((size_t)NH * TT * 32 * 2);
  __hip_bfloat16* Vt   = (__hip_bfloat16*)alloc((size_t)NH * 32 * TT * 2);
  __hip_bfloat16* Ob   = (__hip_bfloat16*)alloc((size_t)TT * DATTN * 2);

  k_f32_to_bf16<<<dim3((TT * DM / 4) / 256), 256, 0, stream>>>(x, Xbf, TT * DM / 4);
  k_f32_to_bf16<<<dim3((DM * DATTN / 4) / 256), 256, 0, stream>>>(ow, OW, DM * DATTN / 4);
  k_pack_wcat<<<dim3((NPROJ * DM / 4) / 256), 256, 0, stream>>>(qsw, ksw, qgw, kgw, vw, Wcat,
                                                                NPROJ * DM / 4);
  k_gemm_bt<1><<<dim3(TT / 128, NPROJ / 128), 256, 0, stream>>>(Xbf, Wcat, (void*)proj,
                                                                TT, NPROJ, DM);
  k_rope_pack<<<dim3(TT * NH / 256), 256, 0, stream>>>(proj, ls, posp, Qp, Kpk, Vt);
  k_attn<<<dim3(2048), 128, 0, stream>>>(Qp, Kpk, Vt, Ob);
  k_gemm_bt<0><<<dim3(TT / 128, DM / 128), 256, 0, stream>>>(Ob, OW, (void*)d_out,
                                                             TT, DM, DATTN);
}